// Round 9
// baseline (465.537 us; speedup 1.0000x reference)
//
#include <hip/hip_runtime.h>
#include <hip/hip_fp16.h>
#include <hip/hip_bf16.h>

#define NB 8
#define NC 64
#define NH 256
#define NW 512
#define ND 16
#define HW (NH * NW)          // 131072
#define EPSV 1e-6f
#define EXT 324               // 18x18 extended pixels
#define RSH 56                // LDS record stride in halves (112 B)
#define TT 4                  // tiles per block (pipelined)

typedef __attribute__((ext_vector_type(8))) short bf16x8;
typedef __attribute__((ext_vector_type(4))) float f32x4;

__device__ __forceinline__ unsigned pack_bf16rn(float aa, float bb) {
    union { __hip_bfloat162 h2; unsigned u; } c;
    c.h2 = __float22bfloat162_rn(float2{aa, bb});
    return c.u;
}
__device__ __forceinline__ float hi_part(float f) {
    return __uint_as_float(__float_as_uint(f) & 0xFFFF0000u);
}
__device__ __forceinline__ unsigned pack_hi2(float aa, float bb) {
    return (__float_as_uint(bb) & 0xFFFF0000u) | (__float_as_uint(aa) >> 16);
}
__device__ __forceinline__ float fdot2f(unsigned ua, unsigned ub, float c) {
#if __has_builtin(__builtin_amdgcn_fdot2)
    typedef __attribute__((ext_vector_type(2))) _Float16 h2t;
    union { unsigned u; h2t h; } A, B;
    A.u = ua; B.u = ub;
    return __builtin_amdgcn_fdot2(A.h, B.h, c, false);
#else
    union { unsigned u; __half2 h; } A, B;
    A.u = ua; B.u = ub;
    float2 fa = __half22float2(A.h), fb = __half22float2(B.h);
    return fmaf(fa.y, fb.y, fmaf(fa.x, fb.x, c));
#endif
}

// ---------------------------------------------------------------------------
// Fully fused NA2D, v9 = v8 math + cross-tile software pipelining.
// Block = 512 threads, processes TT=4 consecutive tiles (16x16 each) with
// double-buffered LDS records. Per iteration: consume(t) [MFMA projection ->
// phi -> LDS], issue x-loads(t+1), raw s_barrier WITHOUT vmcnt drain (manual
// lgkmcnt(0) only), attention+outproj(t). The x-load latency of tile t+1 is
// hidden under attention of tile t.
// ---------------------------------------------------------------------------
__global__ __launch_bounds__(512, 4)
void na2d_fused_v9(const float* __restrict__ x,
                   const float* __restrict__ wqkv,
                   const float* __restrict__ wout,
                   float* __restrict__ y)
{
    __shared__ __align__(16) __half sbuf[2][EXT * RSH];   // 2 x 36288 B

    const int t    = threadIdx.x;
    const int wid  = t >> 6;
    const int lane = t & 63;
    const int lg   = lane >> 4;     // 0..3
    const int lr   = lane & 15;     // 0..15

    // XCD swizzle: 1024 blocks round-robin -> XCD k owns image k.
    const int b   = blockIdx.x & 7;
    const int gid = blockIdx.x >> 3;      // 0..127
    const int by  = gid >> 3;             // 0..15
    const int bx0 = (gid & 7) * TT;       // 0,4,...,28
    const int h0  = by * 16;

    const float* __restrict__ xb = x + (size_t)b * NC * HW;

    // ---- A fragments: wqkv rows, bf16-rn (resident, 24 VGPR) ----
    bf16x8 a[3][2];
    #pragma unroll
    for (int og = 0; og < 3; ++og) {
        const int row = og * 16 + lr;
        #pragma unroll
        for (int ks = 0; ks < 2; ++ks) {
            union { bf16x8 v; unsigned u[4]; } r;
            #pragma unroll
            for (int i = 0; i < 4; ++i)
                r.u[i] = pack_bf16rn(wqkv[row * NC + ks * 32 + lg * 8 + 2 * i],
                                     wqkv[row * NC + ks * 32 + lg * 8 + 2 * i + 1]);
            a[og][ks] = r.v;
        }
    }

    // ---- tile-invariant geometry for this thread's 3 pixel groups ----
    const int pb = wid * 48;              // wave 7: all groups skipped
    int rowoff[3], exm1[3];
    bool vH[3];
    #pragma unroll
    for (int pg = 0; pg < 3; ++pg) {
        const int pe = pb + pg * 16 + lr;
        const int ey = pe / 18;
        exm1[pg] = (pe - ey * 18) - 1;
        int hh = h0 + ey - 1;
        vH[pg] = (unsigned)hh < NH;
        hh = hh < 0 ? 0 : (hh > NH - 1 ? NH - 1 : hh);
        rowoff[pg] = hh * NW;
    }

    float xv[3][16];                      // staging registers (48 VGPR)

    auto issue = [&](int w0n) {
        #pragma unroll
        for (int pg = 0; pg < 3; ++pg) {
            if (pb + pg * 16 < EXT) {     // wave-uniform
                int ww = w0n + exm1[pg];
                ww = ww < 0 ? 0 : (ww > NW - 1 ? NW - 1 : ww);
                const float* xp = xb + rowoff[pg] + ww;
                #pragma unroll
                for (int j = 0; j < 16; ++j)
                    xv[pg][j] = xp[(size_t)((j >> 3) * 32 + lg * 8 + (j & 7)) * HW];
            }
        }
    };

    issue(bx0 * 16);                      // prologue: loads for tile 0

    for (int tt = 0; tt < TT; ++tt) {
        const int w0 = (bx0 + tt) * 16;
        __half* s = sbuf[tt & 1];

        // ---- consume(t): pack -> MFMA -> phi -> LDS records ----
        #pragma unroll
        for (int pg = 0; pg < 3; ++pg) {
            if (pb + pg * 16 < EXT) {
                const int pe = pb + pg * 16 + lr;
                const bool valid = vH[pg] && (unsigned)(w0 + exm1[pg]) < NW;

                union { bf16x8 v; unsigned u[4]; } bh[2], bl[2];
                #pragma unroll
                for (int ks = 0; ks < 2; ++ks)
                    #pragma unroll
                    for (int i = 0; i < 4; ++i) {
                        const float f0 = xv[pg][ks * 8 + 2 * i];
                        const float f1 = xv[pg][ks * 8 + 2 * i + 1];
                        bh[ks].u[i] = pack_hi2(f0, f1);
                        bl[ks].u[i] = pack_hi2(f0 - hi_part(f0), f1 - hi_part(f1));
                    }

                f32x4 acc[3];
                #pragma unroll
                for (int og = 0; og < 3; ++og) {
                    acc[og] = (f32x4)(0.f);
                    #pragma unroll
                    for (int ks = 0; ks < 2; ++ks) {
                        acc[og] = __builtin_amdgcn_mfma_f32_16x16x32_bf16(a[og][ks], bh[ks].v, acc[og], 0, 0, 0);
                        acc[og] = __builtin_amdgcn_mfma_f32_16x16x32_bf16(a[og][ks], bl[ks].v, acc[og], 0, 0, 0);
                    }
                }

                if (pe < EXT) {           // per-lane tail guard (wave 6)
                    #pragma unroll
                    for (int og = 0; og < 3; ++og) {
                        f32x4 v = acc[og];
                        if (og < 2) {     // phi = elu + 1 on q,k
                            #pragma unroll
                            for (int i = 0; i < 4; ++i)
                                v[i] = v[i] > 0.f ? v[i] + 1.f : __expf(v[i]);
                        }
                        if (!valid) v = (f32x4)(0.f);   // zero-pad AFTER phi
                        union { uint2 d; struct { __half2 a2, b2; } h; } pk;
                        pk.h.a2 = __floats2half2_rn(v[0], v[1]);
                        pk.h.b2 = __floats2half2_rn(v[2], v[3]);
                        *reinterpret_cast<uint2*>(&s[pe * RSH + og * 16 + lg * 4]) = pk.d;
                    }
                }
            }
        }

        // ---- issue loads for NEXT tile; stay in flight across barrier ----
        if (tt + 1 < TT) issue(w0 + 16);

        // LDS-write visibility only; deliberately NO vmcnt drain here.
        asm volatile("s_waitcnt lgkmcnt(0)" ::: "memory");
        __builtin_amdgcn_s_barrier();

        // ---- attention (wave-pairs duplicate; channel half by parity) ----
        const int p  = (wid >> 1) * 64 + lane;
        const int py = p >> 4, px = p & 15;

        uint4 q0, q1;
        {
            const __half* qp = &s[((py + 1) * 18 + (px + 1)) * RSH];
            q0 = *reinterpret_cast<const uint4*>(qp);
            q1 = *reinterpret_cast<const uint4*>(qp + 8);
        }

        float sc[9];
        float ssum = 0.f;
        #pragma unroll
        for (int n = 0; n < 9; ++n) {
            const int r = (py + n / 3) * 18 + (px + n % 3);
            const __half* kp = &s[r * RSH + 16];
            const uint4 k0 = *reinterpret_cast<const uint4*>(kp);
            const uint4 k1 = *reinterpret_cast<const uint4*>(kp + 8);
            float sv = 0.f;
            sv = fdot2f(q0.x, k0.x, sv);
            sv = fdot2f(q0.y, k0.y, sv);
            sv = fdot2f(q0.z, k0.z, sv);
            sv = fdot2f(q0.w, k0.w, sv);
            sv = fdot2f(q1.x, k1.x, sv);
            sv = fdot2f(q1.y, k1.y, sv);
            sv = fdot2f(q1.z, k1.z, sv);
            sv = fdot2f(q1.w, k1.w, sv);
            sc[n] = sv;
            ssum += sv;
        }
        const float inv = 1.f / (ssum + EPSV);

        __half2 ovh[8];
        #pragma unroll
        for (int i = 0; i < 8; ++i) ovh[i] = __half2half2(__float2half_rn(0.f));
        #pragma unroll
        for (int n = 0; n < 9; ++n) {
            const int r = (py + n / 3) * 18 + (px + n % 3);
            const __half* vp = &s[r * RSH + 32];
            union { uint4 u; __half2 h[4]; } v0, v1;
            v0.u = *reinterpret_cast<const uint4*>(vp);
            v1.u = *reinterpret_cast<const uint4*>(vp + 8);
            const __half2 wn2 = __half2half2(__float2half_rn(sc[n] * inv));
            #pragma unroll
            for (int i = 0; i < 4; ++i) ovh[i]     = __hfma2(wn2, v0.h[i], ovh[i]);
            #pragma unroll
            for (int i = 0; i < 4; ++i) ovh[4 + i] = __hfma2(wn2, v1.h[i], ovh[4 + i]);
        }

        // ---- scalar out-projection (32 channels per wave parity) ----
        float ov[ND];
        #pragma unroll
        for (int i = 0; i < 8; ++i) {
            const float2 f = __half22float2(ovh[i]);
            ov[2 * i]     = f.x;
            ov[2 * i + 1] = f.y;
        }

        const int chalf = __builtin_amdgcn_readfirstlane(wid & 1);
        const int h = h0 + py, w = w0 + px;
        float* yp = y + (size_t)b * NC * HW + (size_t)(chalf * 32) * HW + h * NW + w;
        const float* wo = wout + (chalf * 32) * ND;
        #pragma unroll 8
        for (int o = 0; o < 32; ++o) {
            float a2 = 0.f;
            #pragma unroll
            for (int d = 0; d < ND; ++d)
                a2 = fmaf(wo[o * ND + d], ov[d], a2);
            yp[(size_t)o * HW] = a2;
        }
    }
}

extern "C" void kernel_launch(void* const* d_in, const int* in_sizes, int n_in,
                              void* d_out, int out_size, void* d_ws, size_t ws_size,
                              hipStream_t stream)
{
    const float* x    = (const float*)d_in[0];
    const float* wqkv = (const float*)d_in[1];
    const float* wout = (const float*)d_in[2];
    float* y = (float*)d_out;

    const int nblocks = NB * (NH / 16) * ((NW / 16) / TT);   // 1024
    na2d_fused_v9<<<nblocks, 512, 0, stream>>>(x, wqkv, wout, y);
}

// Round 10
// 214.652 us; speedup vs baseline: 2.1688x; 2.1688x over previous
//
#include <hip/hip_runtime.h>
#include <hip/hip_fp16.h>
#include <hip/hip_bf16.h>

#define NB 8
#define NC 64
#define NH 256
#define NW 512
#define ND 16
#define HW (NH * NW)          // 131072
#define EPSV 1e-6f
#define EXT 324               // 18x18 extended pixels
#define RSH 48                // LDS record stride in halves (96 B, 16B-aligned fields)

typedef __attribute__((ext_vector_type(8))) short bf16x8;
typedef __attribute__((ext_vector_type(4))) float f32x4;

__device__ __forceinline__ unsigned pack_bf16rn(float aa, float bb) {
    union { __hip_bfloat162 h2; unsigned u; } c;
    c.h2 = __float22bfloat162_rn(float2{aa, bb});
    return c.u;
}
__device__ __forceinline__ float fdot2f(unsigned ua, unsigned ub, float c) {
#if __has_builtin(__builtin_amdgcn_fdot2)
    typedef __attribute__((ext_vector_type(2))) _Float16 h2t;
    union { unsigned u; h2t h; } A, B;
    A.u = ua; B.u = ub;
    return __builtin_amdgcn_fdot2(A.h, B.h, c, false);
#else
    union { unsigned u; __half2 h; } A, B;
    A.u = ua; B.u = ub;
    float2 fa = __half22float2(A.h), fb = __half22float2(B.h);
    return fmaf(fa.y, fb.y, fmaf(fa.x, fb.x, c));
#endif
}

// ---------------------------------------------------------------------------
// Fully fused NA2D, v10 = v8 with (1) LDS <= 32 KB (RSH 48) to test the
// LDS-allocation-granularity occupancy hypothesis, (2) single-term bf16-rn
// x in the qkv MFMA (18 MFMA instead of 36, half the packing VALU).
//  Phase 1: qkv projection via MFMA (W bf16-rn resident, x bf16-rn),
//           phi, fp16 records in LDS (31.1 KB).
//  Phase 2: scores via v_dot2_f32_f16, weighted-V via v_pk_fma_f16
//           (wave-pairs duplicate; channel-half split by wave parity).
//  Phase 3: scalar out-projection 16->64 (wout rows wave-uniform -> s_load).
//  Single barrier total.
// ---------------------------------------------------------------------------
__global__ __launch_bounds__(512, 4)
void na2d_fused_v10(const float* __restrict__ x,
                    const float* __restrict__ wqkv,
                    const float* __restrict__ wout,
                    float* __restrict__ y)
{
    __shared__ __align__(16) __half s[EXT * RSH];   // 31104 B

    const int t    = threadIdx.x;
    const int wid  = t >> 6;
    const int lane = t & 63;
    const int lg   = lane >> 4;     // 0..3
    const int lr   = lane & 15;     // 0..15

    // XCD swizzle: each XCD owns one batch image -> halo reuse in its L2.
    const int wg = (blockIdx.x & 7) * 512 + (blockIdx.x >> 3);
    const int bx = wg & 31;
    const int by = (wg >> 5) & 15;
    const int b  = wg >> 9;
    const int w0 = bx * 16;
    const int h0 = by * 16;

    const float* __restrict__ xb = x + (size_t)b * NC * HW;

    // A fragments: wqkv rows, bf16-rn (24 VGPR resident)
    bf16x8 a[3][2];
    #pragma unroll
    for (int og = 0; og < 3; ++og) {
        const int row = og * 16 + lr;
        #pragma unroll
        for (int ks = 0; ks < 2; ++ks) {
            union { bf16x8 v; unsigned u[4]; } r;
            #pragma unroll
            for (int i = 0; i < 4; ++i)
                r.u[i] = pack_bf16rn(wqkv[row * NC + ks * 32 + lg * 8 + 2 * i],
                                     wqkv[row * NC + ks * 32 + lg * 8 + 2 * i + 1]);
            a[og][ks] = r.v;
        }
    }

    // ---- Phase 1: per-pg load -> pack (bf16-rn) -> MFMA -> phi -> LDS ----
    const int pb = wid * 48;        // wave 7: all pg skipped

    #pragma unroll
    for (int pg = 0; pg < 3; ++pg) {
        if (pb + pg * 16 < EXT) {                  // wave-uniform
            const int pe = pb + pg * 16 + lr;
            const int ey = pe / 18;
            const int ex = pe - ey * 18;
            int hh = h0 + ey - 1;
            int ww = w0 + ex - 1;
            const bool valid = (unsigned)hh < NH && (unsigned)ww < NW;
            hh = hh < 0 ? 0 : (hh > NH - 1 ? NH - 1 : hh);   // clamp: safe addr,
            ww = ww < 0 ? 0 : (ww > NW - 1 ? NW - 1 : ww);   // zeroed at store
            const float* xp = xb + hh * NW + ww;

            float xv[16];
            #pragma unroll
            for (int j = 0; j < 16; ++j)
                xv[j] = xp[(size_t)((j >> 3) * 32 + lg * 8 + (j & 7)) * HW];

            union { bf16x8 v; unsigned u[4]; } bh[2];
            #pragma unroll
            for (int ks = 0; ks < 2; ++ks)
                #pragma unroll
                for (int i = 0; i < 4; ++i)
                    bh[ks].u[i] = pack_bf16rn(xv[ks * 8 + 2 * i], xv[ks * 8 + 2 * i + 1]);

            f32x4 acc[3];
            #pragma unroll
            for (int og = 0; og < 3; ++og) {
                acc[og] = (f32x4)(0.f);
                #pragma unroll
                for (int ks = 0; ks < 2; ++ks)
                    acc[og] = __builtin_amdgcn_mfma_f32_16x16x32_bf16(a[og][ks], bh[ks].v, acc[og], 0, 0, 0);
            }

            if (pe < EXT) {                        // per-lane tail (wave 6)
                #pragma unroll
                for (int og = 0; og < 3; ++og) {
                    f32x4 v = acc[og];
                    if (og < 2) {                  // phi = elu + 1 on q,k
                        #pragma unroll
                        for (int i = 0; i < 4; ++i)
                            v[i] = v[i] > 0.f ? v[i] + 1.f : __expf(v[i]);
                    }
                    if (!valid) v = (f32x4)(0.f);  // zero-pad AFTER phi
                    union { uint2 d; struct { __half2 a2, b2; } h; } pk;
                    pk.h.a2 = __floats2half2_rn(v[0], v[1]);
                    pk.h.b2 = __floats2half2_rn(v[2], v[3]);
                    *reinterpret_cast<uint2*>(&s[pe * RSH + og * 16 + lg * 4]) = pk.d;
                }
            }
        }
    }
    __syncthreads();

    // ---- Phase 2: attention (wave-pairs duplicate; chalf by parity) ----
    const int p  = (wid >> 1) * 64 + lane;
    const int py = p >> 4, px = p & 15;

    uint4 q0, q1;
    {
        const __half* qp = &s[((py + 1) * 18 + (px + 1)) * RSH];
        q0 = *reinterpret_cast<const uint4*>(qp);
        q1 = *reinterpret_cast<const uint4*>(qp + 8);
    }

    float sc[9];
    float ssum = 0.f;
    #pragma unroll
    for (int n = 0; n < 9; ++n) {
        const int r = (py + n / 3) * 18 + (px + n % 3);
        const __half* kp = &s[r * RSH + 16];
        const uint4 k0 = *reinterpret_cast<const uint4*>(kp);
        const uint4 k1 = *reinterpret_cast<const uint4*>(kp + 8);
        float sv = 0.f;
        sv = fdot2f(q0.x, k0.x, sv);
        sv = fdot2f(q0.y, k0.y, sv);
        sv = fdot2f(q0.z, k0.z, sv);
        sv = fdot2f(q0.w, k0.w, sv);
        sv = fdot2f(q1.x, k1.x, sv);
        sv = fdot2f(q1.y, k1.y, sv);
        sv = fdot2f(q1.z, k1.z, sv);
        sv = fdot2f(q1.w, k1.w, sv);
        sc[n] = sv;
        ssum += sv;
    }
    const float inv = 1.f / (ssum + EPSV);

    __half2 ovh[8];
    #pragma unroll
    for (int i = 0; i < 8; ++i) ovh[i] = __half2half2(__float2half_rn(0.f));
    #pragma unroll
    for (int n = 0; n < 9; ++n) {
        const int r = (py + n / 3) * 18 + (px + n % 3);
        const __half* vp = &s[r * RSH + 32];
        union { uint4 u; __half2 h[4]; } v0, v1;
        v0.u = *reinterpret_cast<const uint4*>(vp);
        v1.u = *reinterpret_cast<const uint4*>(vp + 8);
        const __half2 wn2 = __half2half2(__float2half_rn(sc[n] * inv));
        #pragma unroll
        for (int i = 0; i < 4; ++i) ovh[i]     = __hfma2(wn2, v0.h[i], ovh[i]);
        #pragma unroll
        for (int i = 0; i < 4; ++i) ovh[4 + i] = __hfma2(wn2, v1.h[i], ovh[4 + i]);
    }

    // ---- Phase 3: scalar out-projection (32 channels per wave parity) ----
    float ov[ND];
    #pragma unroll
    for (int i = 0; i < 8; ++i) {
        const float2 f = __half22float2(ovh[i]);
        ov[2 * i]     = f.x;
        ov[2 * i + 1] = f.y;
    }

    const int chalf = __builtin_amdgcn_readfirstlane(wid & 1);
    const int h = h0 + py, w = w0 + px;
    float* yp = y + (size_t)b * NC * HW + (size_t)(chalf * 32) * HW + h * NW + w;
    const float* wo = wout + (chalf * 32) * ND;
    #pragma unroll 8
    for (int o = 0; o < 32; ++o) {
        float a2 = 0.f;
        #pragma unroll
        for (int d = 0; d < ND; ++d)
            a2 = fmaf(wo[o * ND + d], ov[d], a2);
        yp[(size_t)o * HW] = a2;
    }
}

extern "C" void kernel_launch(void* const* d_in, const int* in_sizes, int n_in,
                              void* d_out, int out_size, void* d_ws, size_t ws_size,
                              hipStream_t stream)
{
    const float* x    = (const float*)d_in[0];
    const float* wqkv = (const float*)d_in[1];
    const float* wout = (const float*)d_in[2];
    float* y = (float*)d_out;

    const int nblocks = (NW / 16) * (NH / 16) * NB;   // 4096
    na2d_fused_v10<<<nblocks, 512, 0, stream>>>(x, wqkv, wout, y);
}